// Round 2
// baseline (1113.559 us; speedup 1.0000x reference)
//
#include <hip/hip_runtime.h>
#include <stdint.h>

typedef unsigned long long u64;
typedef unsigned u32;
typedef float __attribute__((ext_vector_type(4))) f4raw;

#define K 27
#define S 258
#define ENCMAX (4 * S * S * S)        // 68,694,048 possible keys

// ---- manual grid barrier: all blocks co-resident (enforced by launch_bounds) ----
__device__ __forceinline__ void gbar(int* cnt, int nblk) {
    __syncthreads();
    if (threadIdx.x == 0) {
        __threadfence();                                             // belt
        __hip_atomic_fetch_add(cnt, 1, __ATOMIC_RELEASE, __HIP_MEMORY_SCOPE_AGENT);
        while (__hip_atomic_load(cnt, __ATOMIC_RELAXED, __HIP_MEMORY_SCOPE_AGENT) < nblk)
            __builtin_amdgcn_s_sleep(2);
        (void)__hip_atomic_load(cnt, __ATOMIC_ACQUIRE, __HIP_MEMORY_SCOPE_AGENT);
        __threadfence();                                             // suspenders
    }
    __syncthreads();
}

// ============ fused: mark | tilesum | wprefix | kid | flags | scan ============
__global__ void __launch_bounds__(256, 3)
k_fused(const int* __restrict__ si, int N, int NK, int NT, int NB,
        u64* __restrict__ bits, u64* __restrict__ dupb,
        int* __restrict__ tsums, u32* __restrict__ wprefix,
        int* __restrict__ minE, int* __restrict__ kid,
        int* __restrict__ rank_key, float* __restrict__ out_key,
        float4* __restrict__ outF4, int* __restrict__ barcnt) {
    __shared__ int s[256];
    __shared__ u64 s2[256];
    const int tid = threadIdx.x;
    const int b = blockIdx.x;
    const int nblk = gridDim.x;
    const int gs = nblk * 256;

    // ---- P0: presence bits + exact dup bitmap (atomicOr return) ----
    for (int idx = b * 256 + tid; idx < N * 9; idx += gs) {
        int n = idx / 9, run = idx - n * 9;
        int ox = run / 3, oy = run - ox * 3;
        int bb = si[n], x = si[N + n], y = si[2 * N + n], z = si[3 * N + n];
        unsigned enc0 = (unsigned)(((bb * S + x + ox) * S + (y + oy)) * S + z);
        unsigned w = enc0 >> 6; int bit = enc0 & 63;
        u64 m1 = 7ull << bit;
        u64 old = atomicOr(&bits[w], m1);
        u64 d1 = old & m1;
        if (d1) atomicOr(&dupb[w], d1);                 // rare (~55k total)
        if (bit > 61) {
            u64 m2 = 7ull >> (64 - bit);
            u64 old2 = atomicOr(&bits[w + 1], m2);
            u64 d2 = old2 & m2;
            if (d2) atomicOr(&dupb[w + 1], d2);
        }
    }
    gbar(barcnt + 0, nblk);

    // ---- P1: per-tile popcount sums (popcounts kept in regs for P2) ----
    int pc[16]; int tsum = 0;
    if (b < NT) {
        size_t wb = (size_t)b * 4096 + (size_t)tid * 16;
#pragma unroll
        for (int j = 0; j < 16; j++) { pc[j] = __popcll(bits[wb + j]); tsum += pc[j]; }
        s[tid] = tsum; __syncthreads();
        for (int off = 128; off > 0; off >>= 1) {
            if (tid < off) s[tid] += s[tid + off];
            __syncthreads();
        }
        if (tid == 0) tsums[b] = s[0];
    }
    gbar(barcnt + 1, nblk);

    // ---- P2: word-level exclusive prefix (no bits re-read) ----
    if (b < NT) {
        int pre = 0;
        for (int j = tid; j < b; j += 256) pre += tsums[j];
        s[tid] = pre; __syncthreads();
        for (int off = 128; off > 0; off >>= 1) {
            if (tid < off) s[tid] += s[tid + off];
            __syncthreads();
        }
        int tbase = s[0];
        __syncthreads();
        s[tid] = tsum; __syncthreads();
        for (int off = 1; off < 256; off <<= 1) {
            int t = (tid >= off) ? s[tid - off] : 0;
            __syncthreads();
            s[tid] += t;
            __syncthreads();
        }
        int run = tbase + s[tid] - tsum;
        size_t wb = (size_t)b * 4096 + (size_t)tid * 16;
#pragma unroll
        for (int j = 0; j < 16; j++) { wprefix[wb + j] = (u32)run; run += pc[j]; }
    }
    gbar(barcnt + 2, nblk);

    // ---- P3: dense key id per entry -> REGISTERS; atomicMin only for multi ----
    const int base = b * 4096 + tid * 16;
    int kv[16];
#pragma unroll
    for (int j = 0; j < 16; j++) {
        int e = base + j;
        kv[j] = 0;
        if (e < NK) {
            int n = e / K; int m = e - n * K;
            int ox = m / 9; int rm = m - ox * 9; int oy = rm / 3; int oz = rm - oy * 3;
            int bb = si[n], x = si[N + n], y = si[2 * N + n], z = si[3 * N + n];
            unsigned enc = (unsigned)(((bb * S + x + ox) * S + (y + oy)) * S + (z + oz));
            unsigned w = enc >> 6; int bit = enc & 63;
            int kd = (int)wprefix[w] + __popcll(bits[w] & ((1ull << bit) - 1));
            int multi = (int)((dupb[w] >> bit) & 1);
            kv[j] = multi ? (int)((u32)kd | 0x80000000u) : kd;
            if (multi) atomicMin(&minE[kd], e);          // ~110k only
        }
    }
    gbar(barcnt + 3, nblk);

    // ---- P4: flags (free for singletons) + per-block sums ----
    int fbits = 0;
#pragma unroll
    for (int j = 0; j < 16; j++) {
        int e = base + j;
        int f = 0;
        if (e < NK) {
            int v = kv[j];
            f = (v >= 0) ? 1 : (minE[v & 0x7FFFFFFF] == e ? 1 : 0);
        }
        fbits |= f << j;
    }
    int fsum = __popc(fbits);
    s[tid] = fsum; __syncthreads();
    for (int off = 128; off > 0; off >>= 1) {
        if (tid < off) s[tid] += s[tid + off];
        __syncthreads();
    }
    if (tid == 0) tsums[NT + 1 + b] = s[0];              // bsums region
    gbar(barcnt + 4, nblk);

    // ---- P5: global scan + ranks + out_key + uid in-place + prezero + tail ----
    const int* bsums = tsums + NT + 1;
    u64 acc = 0;
    for (int j = tid; j < NB; j += 256) {
        u64 v = (u64)(u32)bsums[j];
        acc += v << 32;
        if (j < b) acc += v;
    }
    s2[tid] = acc; __syncthreads();
    for (int off = 128; off > 0; off >>= 1) {
        if (tid < off) s2[tid] += s2[tid + off];
        __syncthreads();
    }
    int blockoff = (int)(u32)(s2[0] & 0xFFFFFFFFull);
    int U = (int)(s2[0] >> 32);
    __syncthreads();
    s[tid] = fsum; __syncthreads();
    for (int off = 1; off < 256; off <<= 1) {
        int t = (tid >= off) ? s[tid - off] : 0;
        __syncthreads();
        s[tid] += t;
        __syncthreads();
    }
    int offset = blockoff + s[tid] - fsum;
    float4 zf = {0.f, 0.f, 0.f, 0.f};
    int run = 0;
#pragma unroll
    for (int j = 0; j < 16; j++) {
        int e = base + j;
        if (e < NK) {
            int v = kv[j];
            if ((fbits >> j) & 1) {
                int rank = offset + run;
                int n = e / K; int m = e - n * K;
                int x = si[N + n], y = si[2 * N + n], z = si[3 * N + n];
                int ox = m / 9; int rm = m - ox * 9; int oy = rm / 3; int oz = rm - oy * 3;
                out_key[(size_t)rank * 3 + 0] = (float)(x + ox - 1);
                out_key[(size_t)rank * 3 + 1] = (float)(y + oy - 1);
                out_key[(size_t)rank * 3 + 2] = (float)(z + oz - 1);
                if (v < 0) {                              // multi first-entry
                    int kd = v & 0x7FFFFFFF;
                    rank_key[kd] = rank;
                    kid[e] = rank | 0x40000000;           // uid + atomic tag
                    float4* q = outF4 + (size_t)rank * 8; // pre-zero row
#pragma unroll
                    for (int q8 = 0; q8 < 8; q8++) q[q8] = zf;
                } else {
                    kid[e] = rank;                        // uid, stream tag
                }
                run++;
            } else {
                kid[e] = v;                               // dup non-min: kd|SIGN
            }
        }
    }
    // tail rows >= U: outF=0, out_key=-1
    int rows = NK - U;
    for (int i = b * 256 + tid; i < rows; i += gs) {
        int row = U + i;
        float4* q = outF4 + (size_t)row * 8;
#pragma unroll
        for (int q8 = 0; q8 < 8; q8++) q[q8] = zf;
        out_key[(size_t)row * 3 + 0] = -1.0f;
        out_key[(size_t)row * 3 + 1] = -1.0f;
        out_key[(size_t)row * 3 + 2] = -1.0f;
    }
}

// ---------- final: kernel_map + feature scatter; uid comes straight from kid
__global__ void k_final(const int* __restrict__ ent, const int* __restrict__ rank_key,
                        const float4* __restrict__ feat4,
                        float* __restrict__ km, float* __restrict__ outF, int NK) {
    int total = NK * 8;
    int gs = gridDim.x * blockDim.x;
    for (int idx = blockIdx.x * blockDim.x + threadIdx.x; idx < total; idx += gs) {
        int e = idx >> 3, g = idx & 7;
        int v = ent[e];                               // 8 lanes same addr
        int n = e / K, m = e - n * K;
        float4 val = feat4[(size_t)n * 8 + g];
        int uid, atom;
        if (v < 0)                { uid = rank_key[v & 0x7FFFFFFF]; atom = 1; }   // dup (~2%)
        else if (v & 0x40000000)  { uid = v & 0x3FFFFFFF;           atom = 1; }   // multi first
        else                      { uid = v;                        atom = 0; }   // singleton
        float* dst = outF + (size_t)uid * 32 + g * 4;
        if (atom) {
            atomicAdd(dst + 0, val.x);
            atomicAdd(dst + 1, val.y);
            atomicAdd(dst + 2, val.z);
            atomicAdd(dst + 3, val.w);
        } else {
            f4raw vr = {val.x, val.y, val.z, val.w};
            __builtin_nontemporal_store(vr, (f4raw*)dst);   // 346MB write-once stream
        }
        if (g < 3)
            km[(size_t)e * 3 + g] = (g == 0) ? (float)n
                                   : ((g == 1) ? (float)uid : (float)m);
    }
}

extern "C" void kernel_launch(void* const* d_in, const int* in_sizes, int n_in,
                              void* d_out, int out_size, void* d_ws, size_t ws_size,
                              hipStream_t stream) {
    const int* si = (const int*)d_in[0];
    const float4* feat4 = (const float4*)d_in[1];
    int N = in_sizes[0] / 4;
    int NK = N * K;                            // 2,700,000
    int NKp = (NK + 4095) & ~4095;
    int NB = NKp / 4096;                       // ~660 (co-resident: <=768)

    int NW = (ENCMAX + 63) / 64;               // 1,073,345 bitmap words
    int NT = (NW + 4095) / 4096;               // 263 tiles
    int NWp = NT * 4096;

    float* km = (float*)d_out;                 // [NK,3]
    float* out_key = km + (size_t)NK * 3;      // [NK,3]
    float* outF = km + (size_t)NK * 6;         // [NK,32]

    char* w = (char*)d_ws;
    char* p_bar   = w; w += 64;                               // 8 barrier counters
    char* p_bits  = w; w += ((size_t)NWp * 8 + 15) & ~(size_t)15;
    char* p_dupb  = w; w += ((size_t)NWp * 8 + 15) & ~(size_t)15;
    size_t zbytes = (size_t)(w - (char*)d_ws);       // bar + bits + dupb, one memset
    char* p_tsums = w; w += ((size_t)(NT + 1 + NB + 1) * 4 + 15) & ~(size_t)15;
    char* p_wpref = w; w += ((size_t)NWp * 4 + 15) & ~(size_t)15;
    char* p_minE  = w; w += ((size_t)NK * 4 + 15) & ~(size_t)15;
    char* p_kid   = w; w += ((size_t)NKp * 4 + 15) & ~(size_t)15;
    char* p_rank  = w; w += ((size_t)NK * 4 + 15) & ~(size_t)15;

    int* barcnt   = (int*)p_bar;
    u64* bits     = (u64*)p_bits;
    u64* dupb     = (u64*)p_dupb;
    int* tsums    = (int*)p_tsums;
    u32* wprefix  = (u32*)p_wpref;
    int* minE     = (int*)p_minE;
    int* kid      = (int*)p_kid;
    int* rank_key = (int*)p_rank;

    (void)hipMemsetAsync(d_ws, 0, zbytes, stream);             // bar + bits + dupb
    (void)hipMemsetAsync(minE, 0x7F, (size_t)NK * 4, stream);  // +INF for atomicMin

    k_fused<<<NB, 256, 0, stream>>>(si, N, NK, NT, NB, bits, dupb, tsums, wprefix,
                                    minE, kid, rank_key, out_key, (float4*)outF,
                                    barcnt);
    k_final<<<2048, 256, 0, stream>>>(kid, rank_key, feat4, km, outF, NK);
}

// Round 3
// 641.173 us; speedup vs baseline: 1.7368x; 1.7368x over previous
//
#include <hip/hip_runtime.h>
#include <stdint.h>

typedef unsigned long long u64;
typedef unsigned u32;
typedef float __attribute__((ext_vector_type(4))) f4raw;

#define K 27
#define S 258
#define ENCMAX (4 * S * S * S)        // 68,694,048 possible keys

// Interleaved per-word record, 16B: [u64 bits][u32 dupany][u32 wpre]
// u64 view:  rec[2w]   = bits,  rec[2w+1] = {wpre:hi32, dupany:lo32}
// u32 view:  rec32[4w+2] = dupany, rec32[4w+3] = wpre

// ---------- pass 1: presence bits + whole-word dup flag (atomicOr return) ----
__global__ void k_mark(const int* __restrict__ si, int N, u64* __restrict__ rec) {
    int idx = blockIdx.x * blockDim.x + threadIdx.x;
    if (idx >= N * 9) return;
    int n = idx / 9, run = idx - n * 9;
    int ox = run / 3, oy = run - ox * 3;
    int b = si[n], x = si[N + n], y = si[2 * N + n], z = si[3 * N + n];
    unsigned enc0 = (unsigned)(((b * S + x + ox) * S + (y + oy)) * S + z);
    unsigned w = enc0 >> 6; int bit = enc0 & 63;
    u64 m1 = 7ull << bit;
    u64 old = atomicOr(&rec[2 * (size_t)w], m1);
    if (old & m1) atomicOr((u32*)rec + 4 * (size_t)w + 2, 1u);   // rare
    if (bit > 61) {
        u64 m2 = 7ull >> (64 - bit);
        u64 old2 = atomicOr(&rec[2 * (size_t)(w + 1)], m2);
        if (old2 & m2) atomicOr((u32*)rec + 4 * (size_t)(w + 1) + 2, 1u);
    }
}

// ---------- s1: per-4096-word tile popcount sums ----------
__global__ void s1_tilesum(const u64* __restrict__ rec, int* __restrict__ tsums) {
    __shared__ int s[256];
    int tid = threadIdx.x;
    const u64* p = rec + (size_t)blockIdx.x * 8192;
    int sum = 0;
    for (int j = tid; j < 4096; j += 256) sum += __popcll(p[2 * j]);
    s[tid] = sum; __syncthreads();
    for (int off = 128; off > 0; off >>= 1) {
        if (tid < off) s[tid] += s[tid + off];
        __syncthreads();
    }
    if (tid == 0) tsums[blockIdx.x] = s[0];
}

// ---------- s3: per-word exclusive popcount prefix into rec.wpre ------------
__global__ void s3_wprefix(u64* __restrict__ rec, const int* __restrict__ tsums,
                           int NT) {
    __shared__ int s[256];
    __shared__ int tb;
    int tid = threadIdx.x;
    // fused exclusive prefix over tile sums (<=1024 tiles, L2-hot)
    int pre = 0;
    for (int j = tid; j < (int)blockIdx.x; j += 256) pre += tsums[j];
    s[tid] = pre; __syncthreads();
    for (int off = 128; off > 0; off >>= 1) {
        if (tid < off) s[tid] += s[tid + off];
        __syncthreads();
    }
    if (tid == 0) tb = s[0];
    __syncthreads();
    int tbase = tb;
    size_t wb = (size_t)blockIdx.x * 4096 + (size_t)tid * 16;
    int pc[16]; int tsum = 0;
#pragma unroll
    for (int j = 0; j < 16; j++) { pc[j] = __popcll(rec[2 * (wb + j)]); tsum += pc[j]; }
    s[tid] = tsum; __syncthreads();
    for (int off = 1; off < 256; off <<= 1) {
        int t = (tid >= off) ? s[tid - off] : 0;
        __syncthreads();
        s[tid] += t;
        __syncthreads();
    }
    int run = tbase + s[tid] - tsum;
    u32* rec32 = (u32*)rec;
#pragma unroll
    for (int j = 0; j < 16; j++) { rec32[4 * (wb + j) + 3] = (u32)run; run += pc[j]; }
}

// ---------- pass 2: dense key id; ONE 16B record load per entry-triplet -----
__global__ void k_kid(const int* __restrict__ si, int N,
                      const u64* __restrict__ rec,
                      int* __restrict__ kid, int* __restrict__ minE) {
    int idx = blockIdx.x * blockDim.x + threadIdx.x;
    if (idx >= N * 9) return;
    int n = idx / 9, run = idx - n * 9;
    int ox = run / 3, oy = run - ox * 3;
    int b = si[n], x = si[N + n], y = si[2 * N + n], z = si[3 * N + n];
    unsigned enc0 = (unsigned)(((b * S + x + ox) * S + (y + oy)) * S + z);
    unsigned w = enc0 >> 6; int bit = enc0 & 63;
    ulonglong2 r0 = *(const ulonglong2*)(rec + 2 * (size_t)w);
    u64 bb0 = r0.x; u32 du0 = (u32)r0.y; u32 wp0 = (u32)(r0.y >> 32);
    u64 bb1 = 0; u32 du1 = 0, wp1 = 0;
    if (bit > 61) {                                  // triplet crosses a word
        ulonglong2 r1 = *(const ulonglong2*)(rec + 2 * (size_t)(w + 1));
        bb1 = r1.x; du1 = (u32)r1.y; wp1 = (u32)(r1.y >> 32);
    }
    int e0 = n * K + run * 3;
#pragma unroll
    for (int oz = 0; oz < 3; ++oz) {
        unsigned enc = enc0 + oz;
        int bit2 = enc & 63;
        bool hi = (enc >> 6) != w;
        u64 bbw = hi ? bb1 : bb0;
        u32 wp  = hi ? wp1 : wp0;
        u32 du  = hi ? du1 : du0;
        int kd = (int)wp + __popcll(bbw & ((1ull << bit2) - 1));
        int multi = (du != 0);                       // whole-word dup flag
        kid[e0 + oz] = multi ? (int)((u32)kd | 0x80000000u) : kd;
        if (multi) atomicMin(&minE[kd], e0 + oz);    // ~135k only
    }
}

// ---------- pass 3: per-block flag sums (flag free for singletons) ----------
__global__ void k_flagsum(const int* __restrict__ kid, const int* __restrict__ minE,
                          int NK, int* __restrict__ bsums) {
    __shared__ int s[256];
    int tid = threadIdx.x;
    int base = blockIdx.x * 4096 + tid * 16;
    int kv[16];
    *(int4*)(kv + 0)  = *(const int4*)(kid + base + 0);
    *(int4*)(kv + 4)  = *(const int4*)(kid + base + 4);
    *(int4*)(kv + 8)  = *(const int4*)(kid + base + 8);
    *(int4*)(kv + 12) = *(const int4*)(kid + base + 12);
    int sum = 0;
#pragma unroll
    for (int j = 0; j < 16; j++) {
        int e = base + j;
        if (e < NK) {
            int v = kv[j];
            sum += (v >= 0) ? 1 : (minE[v & 0x7FFFFFFF] == e ? 1 : 0);
        }
    }
    s[tid] = sum; __syncthreads();
    for (int off = 128; off > 0; off >>= 1) {
        if (tid < off) s[tid] += s[tid + off];
        __syncthreads();
    }
    if (tid == 0) bsums[blockIdx.x] = s[0];
}

// ---------- scan C: ranks, out_key, uid written IN-PLACE into kid ----------
__global__ void k_scanC(int* __restrict__ kid, const int* __restrict__ minE,
                        const int* __restrict__ bsums, const int* __restrict__ si,
                        int N, int NK, int NB,
                        float* __restrict__ out_key, int* __restrict__ rank_key,
                        float4* __restrict__ outF4) {
    __shared__ int s[256];
    __shared__ u64 s2[256];
    int tid = threadIdx.x;
    // fused scan of bsums: low 32 = exclusive prefix at blockIdx, high 32 = total U
    u64 acc = 0;
    for (int j = tid; j < NB; j += 256) {
        u64 b = (u64)(u32)bsums[j];
        acc += b << 32;
        if (j < (int)blockIdx.x) acc += b;
    }
    s2[tid] = acc; __syncthreads();
    for (int off = 128; off > 0; off >>= 1) {
        if (tid < off) s2[tid] += s2[tid + off];
        __syncthreads();
    }
    int blockoff = (int)(u32)(s2[0] & 0xFFFFFFFFull);
    int U = (int)(s2[0] >> 32);

    int base = blockIdx.x * 4096 + tid * 16;
    int kv[16];
    *(int4*)(kv + 0)  = *(const int4*)(kid + base + 0);
    *(int4*)(kv + 4)  = *(const int4*)(kid + base + 4);
    *(int4*)(kv + 8)  = *(const int4*)(kid + base + 8);
    *(int4*)(kv + 12) = *(const int4*)(kid + base + 12);
    int fbits = 0;
#pragma unroll
    for (int j = 0; j < 16; j++) {
        int e = base + j;
        int f = 0;
        if (e < NK) {
            int v = kv[j];
            f = (v >= 0) ? 1 : (minE[v & 0x7FFFFFFF] == e ? 1 : 0);
        }
        fbits |= f << j;
    }
    int tsum = __popc(fbits);
    s[tid] = tsum; __syncthreads();
    for (int off = 1; off < 256; off <<= 1) {
        int t = (tid >= off) ? s[tid - off] : 0;
        __syncthreads();
        s[tid] += t;
        __syncthreads();
    }
    int offset = blockoff + s[tid] - tsum;
    float4 zf = {0.f, 0.f, 0.f, 0.f};
    int run = 0;
#pragma unroll
    for (int j = 0; j < 16; j++) {
        int e = base + j;
        if ((fbits >> j) & 1) {
            int rank = offset + run;
            int n = e / K; int m = e - n * K;
            int x = si[N + n], y = si[2 * N + n], z = si[3 * N + n];
            int ox = m / 9; int rm = m - ox * 9; int oy = rm / 3; int oz = rm - oy * 3;
            out_key[(size_t)rank * 3 + 0] = (float)(x + ox - 1);
            out_key[(size_t)rank * 3 + 1] = (float)(y + oy - 1);
            out_key[(size_t)rank * 3 + 2] = (float)(z + oz - 1);
            int v = kv[j];
            if (v < 0) {                                  // multi first-entry
                int kd = v & 0x7FFFFFFF;
                rank_key[kd] = rank;
                kid[e] = rank | 0x40000000;               // uid + atomic tag
                float4* q = outF4 + (size_t)rank * 8;     // pre-zero row
#pragma unroll
                for (int q8 = 0; q8 < 8; q8++) q[q8] = zf;
            } else {
                kid[e] = rank;                            // uid, stream tag
            }
            run++;
        }
        // non-flagged dup entries keep kd | 0x80000000 in kid[e]
    }
    // tail rows >= U: outF=0, out_key=-1
    int rows = NK - U;
    int gs = gridDim.x * blockDim.x;
    for (int i = blockIdx.x * blockDim.x + tid; i < rows; i += gs) {
        int row = U + i;
        float4* q = outF4 + (size_t)row * 8;
#pragma unroll
        for (int q8 = 0; q8 < 8; q8++) q[q8] = zf;
        out_key[(size_t)row * 3 + 0] = -1.0f;
        out_key[(size_t)row * 3 + 1] = -1.0f;
        out_key[(size_t)row * 3 + 2] = -1.0f;
    }
}

// ---------- final: kernel_map + feature scatter; uid comes straight from kid
__global__ void k_final(const int* __restrict__ ent, const int* __restrict__ rank_key,
                        const float4* __restrict__ feat4,
                        float* __restrict__ km, float* __restrict__ outF, int NK) {
    int idx = blockIdx.x * blockDim.x + threadIdx.x;
    if (idx >= NK * 8) return;
    int e = idx >> 3, g = idx & 7;
    int v = ent[e];                               // 8 lanes same addr
    int n = e / K, m = e - n * K;
    float4 val = feat4[(size_t)n * 8 + g];
    int uid, atom;
    if (v < 0)                { uid = rank_key[v & 0x7FFFFFFF]; atom = 1; }   // dup
    else if (v & 0x40000000)  { uid = v & 0x3FFFFFFF;           atom = 1; }   // multi first
    else                      { uid = v;                        atom = 0; }   // singleton
    float* dst = outF + (size_t)uid * 32 + g * 4;
    if (atom) {
        atomicAdd(dst + 0, val.x);
        atomicAdd(dst + 1, val.y);
        atomicAdd(dst + 2, val.z);
        atomicAdd(dst + 3, val.w);
    } else {
        f4raw vr = {val.x, val.y, val.z, val.w};
        __builtin_nontemporal_store(vr, (f4raw*)dst);   // 346MB write-once stream
    }
    if (g < 3)
        km[(size_t)e * 3 + g] = (g == 0) ? (float)n
                               : ((g == 1) ? (float)uid : (float)m);
}

extern "C" void kernel_launch(void* const* d_in, const int* in_sizes, int n_in,
                              void* d_out, int out_size, void* d_ws, size_t ws_size,
                              hipStream_t stream) {
    const int* si = (const int*)d_in[0];
    const float4* feat4 = (const float4*)d_in[1];
    int N = in_sizes[0] / 4;
    int NK = N * K;                            // 2,700,000
    int NKp = (NK + 4095) & ~4095;
    int NB = NKp / 4096;                       // ~660

    int NW = (ENCMAX + 63) / 64;               // 1,073,345 bitmap words
    int NT = (NW + 4095) / 4096;               // 263 tiles
    int NWp = NT * 4096;

    float* km = (float*)d_out;                 // [NK,3]
    float* out_key = km + (size_t)NK * 3;      // [NK,3]
    float* outF = km + (size_t)NK * 6;         // [NK,32]

    char* w = (char*)d_ws;
    char* p_rec   = w; w += ((size_t)NWp * 16 + 15) & ~(size_t)15;  // interleaved records
    size_t zbytes = (size_t)(w - (char*)d_ws);       // rec zeroed (bits+dupany)
    char* p_tsums = w; w += ((size_t)(NT + 1) * 4 + 15) & ~(size_t)15;
    char* p_minE  = w; w += ((size_t)NK * 4 + 15) & ~(size_t)15;
    char* p_kid   = w; w += ((size_t)NKp * 4 + 15) & ~(size_t)15;
    char* p_rank  = w; w += ((size_t)NK * 4 + 15) & ~(size_t)15;
    char* p_bsums = w; w += ((size_t)(NB + 1) * 4 + 15) & ~(size_t)15;

    u64* rec      = (u64*)p_rec;
    int* tsums    = (int*)p_tsums;
    int* minE     = (int*)p_minE;
    int* kid      = (int*)p_kid;
    int* rank_key = (int*)p_rank;
    int* bsums    = (int*)p_bsums;

    (void)hipMemsetAsync(d_ws, 0, zbytes, stream);             // records
    (void)hipMemsetAsync(minE, 0x7F, (size_t)NK * 4, stream);  // +INF for atomicMin

    int nb9 = (N * 9 + 255) / 256;
    k_mark<<<nb9, 256, 0, stream>>>(si, N, rec);
    s1_tilesum<<<NT, 256, 0, stream>>>(rec, tsums);
    s3_wprefix<<<NT, 256, 0, stream>>>(rec, tsums, NT);
    k_kid<<<nb9, 256, 0, stream>>>(si, N, rec, kid, minE);
    k_flagsum<<<NB, 256, 0, stream>>>(kid, minE, NK, bsums);
    k_scanC<<<NB, 256, 0, stream>>>(kid, minE, bsums, si, N, NK, NB,
                                    out_key, rank_key, (float4*)outF);
    k_final<<<(NK * 8 + 255) / 256, 256, 0, stream>>>(kid, rank_key, feat4,
                                                      km, outF, NK);
}

// Round 4
// 636.093 us; speedup vs baseline: 1.7506x; 1.0080x over previous
//
#include <hip/hip_runtime.h>
#include <stdint.h>

typedef unsigned long long u64;
typedef unsigned u32;
typedef float __attribute__((ext_vector_type(4))) f4raw;

#define K 27
#define S 258
#define ENCMAX (4 * S * S * S)        // 68,694,048 possible keys

// ---- manual grid barrier (all blocks co-resident; used only at NT=263 blocks)
__device__ __forceinline__ void gbar(int* cnt, int nblk) {
    __syncthreads();
    if (threadIdx.x == 0) {
        __threadfence();
        __hip_atomic_fetch_add(cnt, 1, __ATOMIC_RELEASE, __HIP_MEMORY_SCOPE_AGENT);
        while (__hip_atomic_load(cnt, __ATOMIC_RELAXED, __HIP_MEMORY_SCOPE_AGENT) < nblk)
            __builtin_amdgcn_s_sleep(2);
        (void)__hip_atomic_load(cnt, __ATOMIC_ACQUIRE, __HIP_MEMORY_SCOPE_AGENT);
        __threadfence();
    }
    __syncthreads();
}

// ---------- pass 1: presence bits + exact dup bits (compact atomic tables) ---
__global__ void k_mark(const int* __restrict__ si, int N,
                       u64* __restrict__ bits, u64* __restrict__ dupb) {
    int idx = blockIdx.x * blockDim.x + threadIdx.x;
    if (idx >= N * 9) return;
    int n = idx / 9, run = idx - n * 9;
    int ox = run / 3, oy = run - ox * 3;
    int b = si[n], x = si[N + n], y = si[2 * N + n], z = si[3 * N + n];
    unsigned enc0 = (unsigned)(((b * S + x + ox) * S + (y + oy)) * S + z);
    unsigned w = enc0 >> 6; int bit = enc0 & 63;
    u64 m1 = 7ull << bit;
    u64 old = atomicOr(&bits[w], m1);
    u64 d1 = old & m1;
    if (d1) atomicOr(&dupb[w], d1);                 // rare (~55k total)
    if (bit > 61) {
        u64 m2 = 7ull >> (64 - bit);
        u64 old2 = atomicOr(&bits[w + 1], m2);
        u64 d2 = old2 & m2;
        if (d2) atomicOr(&dupb[w + 1], d2);
    }
}

// ---------- s13: tile sums + word prefix + 16B gather-table build (1 dispatch)
// gt[2w] = bits word; gt[2w+1] = wpre | (dup-in-word << 31) in low 32 bits.
__global__ void __launch_bounds__(256, 2)
k_s13(const u64* __restrict__ bits, const u64* __restrict__ dupb,
      int* __restrict__ tsums, u64* __restrict__ gt, int* __restrict__ barcnt) {
    __shared__ int s[256];
    int tid = threadIdx.x;
    int b = blockIdx.x;
    size_t wb = (size_t)b * 4096 + (size_t)tid * 16;
    u64 bb[16]; int pc[16]; int tsum = 0;
#pragma unroll
    for (int j = 0; j < 16; j++) { bb[j] = bits[wb + j]; pc[j] = __popcll(bb[j]); tsum += pc[j]; }
    s[tid] = tsum; __syncthreads();
    for (int off = 128; off > 0; off >>= 1) {
        if (tid < off) s[tid] += s[tid + off];
        __syncthreads();
    }
    if (tid == 0) tsums[b] = s[0];
    gbar(barcnt, gridDim.x);
    // exclusive prefix over tile sums for tiles < b (tsums L2-hot, <=1024 ints)
    int pre = 0;
    for (int j = tid; j < b; j += 256) pre += tsums[j];
    s[tid] = pre; __syncthreads();
    for (int off = 128; off > 0; off >>= 1) {
        if (tid < off) s[tid] += s[tid + off];
        __syncthreads();
    }
    int tbase = s[0]; __syncthreads();
    s[tid] = tsum; __syncthreads();
    for (int off = 1; off < 256; off <<= 1) {
        int t = (tid >= off) ? s[tid - off] : 0;
        __syncthreads();
        s[tid] += t;
        __syncthreads();
    }
    int run = tbase + s[tid] - tsum;
#pragma unroll
    for (int j = 0; j < 16; j++) {
        u32 dup = (dupb[wb + j] != 0ull) ? 0x80000000u : 0u;
        gt[2 * (wb + j)]     = bb[j];
        gt[2 * (wb + j) + 1] = (u64)((u32)run | dup);
        run += pc[j];
    }
}

// ---------- pass 2: dense key id; ONE 16B gather per entry-triplet ----------
__global__ void k_kid(const int* __restrict__ si, int N,
                      const u64* __restrict__ gt,
                      int* __restrict__ kid, int* __restrict__ minE) {
    int idx = blockIdx.x * blockDim.x + threadIdx.x;
    if (idx >= N * 9) return;
    int n = idx / 9, run = idx - n * 9;
    int ox = run / 3, oy = run - ox * 3;
    int b = si[n], x = si[N + n], y = si[2 * N + n], z = si[3 * N + n];
    unsigned enc0 = (unsigned)(((b * S + x + ox) * S + (y + oy)) * S + z);
    unsigned w = enc0 >> 6; int bit = enc0 & 63;
    ulonglong2 r0 = *(const ulonglong2*)(gt + 2 * (size_t)w);
    u64 bb0 = r0.x; u32 q0 = (u32)r0.y;
    u64 bb1 = 0; u32 q1 = 0;
    if (bit > 61) {                                  // triplet crosses a word
        ulonglong2 r1 = *(const ulonglong2*)(gt + 2 * (size_t)(w + 1));
        bb1 = r1.x; q1 = (u32)r1.y;
    }
    int e0 = n * K + run * 3;
#pragma unroll
    for (int oz = 0; oz < 3; ++oz) {
        unsigned enc = enc0 + oz;
        int bit2 = enc & 63;
        bool hi = (enc >> 6) != w;
        u64 bbw = hi ? bb1 : bb0;
        u32 q   = hi ? q1 : q0;
        int kd = (int)(q & 0x7FFFFFFFu) + __popcll(bbw & ((1ull << bit2) - 1));
        int multi = (int)(q >> 31);                  // whole-word dup flag
        kid[e0 + oz] = multi ? (int)((u32)kd | 0x80000000u) : kd;
        if (multi) atomicMin(&minE[kd], e0 + oz);    // ~135k only
    }
}

// ---------- pass 3: per-block flag sums (flag free for singletons) ----------
__global__ void k_flagsum(const int* __restrict__ kid, const int* __restrict__ minE,
                          int NK, int* __restrict__ bsums) {
    __shared__ int s[256];
    int tid = threadIdx.x;
    int base = blockIdx.x * 4096 + tid * 16;
    int kv[16];
    *(int4*)(kv + 0)  = *(const int4*)(kid + base + 0);
    *(int4*)(kv + 4)  = *(const int4*)(kid + base + 4);
    *(int4*)(kv + 8)  = *(const int4*)(kid + base + 8);
    *(int4*)(kv + 12) = *(const int4*)(kid + base + 12);
    int sum = 0;
#pragma unroll
    for (int j = 0; j < 16; j++) {
        int e = base + j;
        if (e < NK) {
            int v = kv[j];
            sum += (v >= 0) ? 1 : (minE[v & 0x7FFFFFFF] == e ? 1 : 0);
        }
    }
    s[tid] = sum; __syncthreads();
    for (int off = 128; off > 0; off >>= 1) {
        if (tid < off) s[tid] += s[tid + off];
        __syncthreads();
    }
    if (tid == 0) bsums[blockIdx.x] = s[0];
}

// ---------- scan C: ranks, out_key, uid written IN-PLACE into kid ----------
__global__ void k_scanC(int* __restrict__ kid, const int* __restrict__ minE,
                        const int* __restrict__ bsums, const int* __restrict__ si,
                        int N, int NK, int NB,
                        float* __restrict__ out_key, int* __restrict__ rank_key,
                        float4* __restrict__ outF4) {
    __shared__ int s[256];
    __shared__ u64 s2[256];
    int tid = threadIdx.x;
    // fused scan of bsums: low 32 = exclusive prefix at blockIdx, high 32 = total U
    u64 acc = 0;
    for (int j = tid; j < NB; j += 256) {
        u64 b = (u64)(u32)bsums[j];
        acc += b << 32;
        if (j < (int)blockIdx.x) acc += b;
    }
    s2[tid] = acc; __syncthreads();
    for (int off = 128; off > 0; off >>= 1) {
        if (tid < off) s2[tid] += s2[tid + off];
        __syncthreads();
    }
    int blockoff = (int)(u32)(s2[0] & 0xFFFFFFFFull);
    int U = (int)(s2[0] >> 32);

    int base = blockIdx.x * 4096 + tid * 16;
    int kv[16];
    *(int4*)(kv + 0)  = *(const int4*)(kid + base + 0);
    *(int4*)(kv + 4)  = *(const int4*)(kid + base + 4);
    *(int4*)(kv + 8)  = *(const int4*)(kid + base + 8);
    *(int4*)(kv + 12) = *(const int4*)(kid + base + 12);
    int fbits = 0;
#pragma unroll
    for (int j = 0; j < 16; j++) {
        int e = base + j;
        int f = 0;
        if (e < NK) {
            int v = kv[j];
            f = (v >= 0) ? 1 : (minE[v & 0x7FFFFFFF] == e ? 1 : 0);
        }
        fbits |= f << j;
    }
    int tsum = __popc(fbits);
    s[tid] = tsum; __syncthreads();
    for (int off = 1; off < 256; off <<= 1) {
        int t = (tid >= off) ? s[tid - off] : 0;
        __syncthreads();
        s[tid] += t;
        __syncthreads();
    }
    int offset = blockoff + s[tid] - tsum;
    float4 zf = {0.f, 0.f, 0.f, 0.f};
    int run = 0;
#pragma unroll
    for (int j = 0; j < 16; j++) {
        int e = base + j;
        if ((fbits >> j) & 1) {
            int rank = offset + run;
            int n = e / K; int m = e - n * K;
            int x = si[N + n], y = si[2 * N + n], z = si[3 * N + n];
            int ox = m / 9; int rm = m - ox * 9; int oy = rm / 3; int oz = rm - oy * 3;
            out_key[(size_t)rank * 3 + 0] = (float)(x + ox - 1);
            out_key[(size_t)rank * 3 + 1] = (float)(y + oy - 1);
            out_key[(size_t)rank * 3 + 2] = (float)(z + oz - 1);
            int v = kv[j];
            if (v < 0) {                                  // multi first-entry
                int kd = v & 0x7FFFFFFF;
                rank_key[kd] = rank;
                kid[e] = rank | 0x40000000;               // uid + atomic tag
                float4* q = outF4 + (size_t)rank * 8;     // pre-zero row
#pragma unroll
                for (int q8 = 0; q8 < 8; q8++) q[q8] = zf;
            } else {
                kid[e] = rank;                            // uid, stream tag
            }
            run++;
        }
        // non-flagged dup entries keep kd | 0x80000000 in kid[e]
    }
    // tail rows >= U: outF=0, out_key=-1
    int rows = NK - U;
    int gs = gridDim.x * blockDim.x;
    for (int i = blockIdx.x * blockDim.x + tid; i < rows; i += gs) {
        int row = U + i;
        float4* q = outF4 + (size_t)row * 8;
#pragma unroll
        for (int q8 = 0; q8 < 8; q8++) q[q8] = zf;
        out_key[(size_t)row * 3 + 0] = -1.0f;
        out_key[(size_t)row * 3 + 1] = -1.0f;
        out_key[(size_t)row * 3 + 2] = -1.0f;
    }
}

// ---------- final: kernel_map + feature scatter; uid comes straight from kid
__global__ void k_final(const int* __restrict__ ent, const int* __restrict__ rank_key,
                        const float4* __restrict__ feat4,
                        float* __restrict__ km, float* __restrict__ outF, int NK) {
    int total = NK * 8;
    int gs = gridDim.x * blockDim.x;
    for (int idx = blockIdx.x * blockDim.x + threadIdx.x; idx < total; idx += gs) {
        int e = idx >> 3, g = idx & 7;
        int v = ent[e];                               // 8 lanes same addr
        int n = e / K, m = e - n * K;
        float4 val = feat4[(size_t)n * 8 + g];
        int uid, atom;
        if (v < 0)                { uid = rank_key[v & 0x7FFFFFFF]; atom = 1; }   // dup
        else if (v & 0x40000000)  { uid = v & 0x3FFFFFFF;           atom = 1; }   // multi first
        else                      { uid = v;                        atom = 0; }   // singleton
        float* dst = outF + (size_t)uid * 32 + g * 4;
        if (atom) {
            atomicAdd(dst + 0, val.x);
            atomicAdd(dst + 1, val.y);
            atomicAdd(dst + 2, val.z);
            atomicAdd(dst + 3, val.w);
        } else {
            f4raw vr = {val.x, val.y, val.z, val.w};
            __builtin_nontemporal_store(vr, (f4raw*)dst);   // 346MB write-once stream
        }
        if (g < 3)
            km[(size_t)e * 3 + g] = (g == 0) ? (float)n
                                   : ((g == 1) ? (float)uid : (float)m);
    }
}

extern "C" void kernel_launch(void* const* d_in, const int* in_sizes, int n_in,
                              void* d_out, int out_size, void* d_ws, size_t ws_size,
                              hipStream_t stream) {
    const int* si = (const int*)d_in[0];
    const float4* feat4 = (const float4*)d_in[1];
    int N = in_sizes[0] / 4;
    int NK = N * K;                            // 2,700,000
    int NKp = (NK + 4095) & ~4095;
    int NB = NKp / 4096;                       // ~660

    int NW = (ENCMAX + 63) / 64;               // 1,073,345 bitmap words
    int NT = (NW + 4095) / 4096;               // 263 tiles (co-resident for gbar)
    int NWp = NT * 4096;

    float* km = (float*)d_out;                 // [NK,3]
    float* out_key = km + (size_t)NK * 3;      // [NK,3]
    float* outF = km + (size_t)NK * 6;         // [NK,32]

    char* w = (char*)d_ws;
    char* p_bar   = w; w += 64;                // barrier counter (zeroed)
    char* p_bits  = w; w += ((size_t)NWp * 8 + 15) & ~(size_t)15;
    char* p_dupb  = w; w += ((size_t)NWp * 8 + 15) & ~(size_t)15;
    size_t zbytes = (size_t)(w - (char*)d_ws); // bar + bits + dupb, one memset
    char* p_gt    = w; w += ((size_t)NWp * 16 + 15) & ~(size_t)15;  // gather table
    char* p_tsums = w; w += ((size_t)(NT + 1) * 4 + 15) & ~(size_t)15;
    char* p_minE  = w; w += ((size_t)NK * 4 + 15) & ~(size_t)15;
    char* p_kid   = w; w += ((size_t)NKp * 4 + 15) & ~(size_t)15;
    char* p_rank  = w; w += ((size_t)NK * 4 + 15) & ~(size_t)15;
    char* p_bsums = w; w += ((size_t)(NB + 1) * 4 + 15) & ~(size_t)15;

    int* barcnt   = (int*)p_bar;
    u64* bits     = (u64*)p_bits;
    u64* dupb     = (u64*)p_dupb;
    u64* gt       = (u64*)p_gt;
    int* tsums    = (int*)p_tsums;
    int* minE     = (int*)p_minE;
    int* kid      = (int*)p_kid;
    int* rank_key = (int*)p_rank;
    int* bsums    = (int*)p_bsums;

    (void)hipMemsetAsync(d_ws, 0, zbytes, stream);             // bar + bits + dupb
    (void)hipMemsetAsync(minE, 0x7F, (size_t)NK * 4, stream);  // +INF for atomicMin

    int nb9 = (N * 9 + 255) / 256;
    k_mark<<<nb9, 256, 0, stream>>>(si, N, bits, dupb);
    k_s13<<<NT, 256, 0, stream>>>(bits, dupb, tsums, gt, barcnt);
    k_kid<<<nb9, 256, 0, stream>>>(si, N, gt, kid, minE);
    k_flagsum<<<NB, 256, 0, stream>>>(kid, minE, NK, bsums);
    k_scanC<<<NB, 256, 0, stream>>>(kid, minE, bsums, si, N, NK, NB,
                                    out_key, rank_key, (float4*)outF);
    k_final<<<2048, 256, 0, stream>>>(kid, rank_key, feat4, km, outF, NK);
}